// Round 12
// baseline (646.024 us; speedup 1.0000x reference)
//
#include <hip/hip_runtime.h>
#include <hip/hip_bf16.h>

// Problem constants (match reference)
static constexpr int N_NODES  = 100000;
static constexpr int N_EDGES  = 400000;
static constexpr int DRUG_DIM = 75;
static constexpr int OUT_C    = 256;   // OUT
static constexpr int N_GRAPH  = 2048;  // G
static constexpr int B_CL     = 2048;  // B
static constexpr int CLINE_DIM= 954;

using bf16 = __hip_bfloat16;
using short8 = __attribute__((ext_vector_type(8))) short;
using f32x4  = __attribute__((ext_vector_type(4))) float;

template<class A, class B> struct is_same_t { static constexpr bool v = false; };
template<class A> struct is_same_t<A, A>   { static constexpr bool v = true;  };

// ---------- load/store helpers ----------
__device__ __forceinline__ float ldf(const float* p) { return *p; }
__device__ __forceinline__ float ldf(const bf16* p)  { return __bfloat162float(*p); }
__device__ __forceinline__ void  stf(float* p, float v) { *p = v; }
__device__ __forceinline__ void  stf(bf16* p, float v)  { *p = __float2bfloat16(v); }
__device__ __forceinline__ float bfu(unsigned short u) { return __uint_as_float(((unsigned)u) << 16); }
__device__ __forceinline__ unsigned short f2bu(float f) {
    bf16 h = __float2bfloat16(f);
    return *reinterpret_cast<unsigned short*>(&h);
}

// async global -> LDS, 16B per lane; LDS dest = uniform base + lane*16
__device__ __forceinline__ void gload_lds16(const void* g, void* l) {
    __builtin_amdgcn_global_load_lds(
        (const __attribute__((address_space(1))) void*)g,
        (__attribute__((address_space(3))) void*)l, 16, 0, 0);
}

// ================= input/weight prep =================
__global__ __launch_bounds__(256)
void convert_a_kernel(const float* __restrict__ A, bf16* __restrict__ Ab,
                      int K, int Kpad, int total)
{
    int idx = blockIdx.x * 256 + threadIdx.x;
    if (idx >= total) return;
    int r = idx / Kpad, k = idx - r * Kpad;
    float f = (k < K) ? A[(size_t)r * K + k] : 0.f;
    Ab[idx] = __float2bfloat16(f);
}

// all weight transposes in one launch; NW is always 256
struct WtJob  { const float* W; bf16* Wt; int K; int n0; int Kpad; };
struct WtJobs { WtJob j[8]; };
__global__ __launch_bounds__(256)
void convert_wt8_kernel(WtJobs jobs)
{
    WtJob jb = jobs.j[blockIdx.y];
    int n = blockIdx.x;
    for (int k = threadIdx.x; k < jb.Kpad; k += 256) {
        float f = (k < jb.K) ? jb.W[(size_t)k * 256 + n] : 0.f;
        jb.Wt[(size_t)(jb.n0 + n) * jb.Kpad + k] = __float2bfloat16(f);
    }
}

__global__ __launch_bounds__(256)
void concat3_kernel(const float* __restrict__ a, const float* __restrict__ b,
                    const float* __restrict__ c, float* __restrict__ out)
{
    int i = blockIdx.x * 256 + threadIdx.x;
    if (i < 256)      out[i] = a[i];
    else if (i < 512) out[i] = b[i - 256];
    else if (i < 768) out[i] = c[i - 512];
}

// ================= MFMA GEMM: 64x256 tile, BK=32 DOUBLE-BUFFERED, 40KB LDS ====
// Plane-split output: column slab [ntile*256, +256) -> plane ntile of C:
// C + ntile*PS + row*256 + col.  A bf16 [M][K], K mult of 64 (hence of 32),
// M mult of 16.  4 waves (1x4 col slabs).
// LDS relation (per 32-elem row): LDS[row][chunk] = data[row][chunk ^ ((row>>1)&3)]
// (chunk = 16B unit), achieved via pre-swizzled GLOBAL source; LDS dest linear.
// Pipeline: stage(buf[t+1]) issued BEFORE compute(buf[t]); the end-of-step
// barrier drains loads that overlapped the 16-MFMA compute phase.
template<int ACT, typename TO>
__global__ __launch_bounds__(256)
void mfma_gemm_kernel(const bf16* __restrict__ A, const bf16* __restrict__ Wt,
                      const float* __restrict__ bias, const bf16* __restrict__ res,
                      TO* __restrict__ C, int M, int K, size_t PS)
{
    __shared__ alignas(16) short As2[2][64 * 32];    // 2 x 4 KB
    __shared__ alignas(16) short Bs2[2][256 * 32];   // 2 x 16 KB
    const int ntile = blockIdx.x, mtile = blockIdx.y;
    const int tid = threadIdx.x;
    const int lane = tid & 63, wid = tid >> 6;   // wave col = wid (0..3)

    f32x4 acc[4][4] = {};

    // staging: 20 issues of 1KB (A: 4, B: 16), 5 per wave; each issue = 16 rows x 64B
    const int l4 = lane >> 2;                 // row within issue (0..15)
    const int schunk = (lane & 3) ^ ((lane >> 3) & 3);   // pre-swizzled src 16B-chunk
    auto stage = [&](int b, int k0) {
        #pragma unroll
        for (int i = 0; i < 5; ++i) {
            const int ci = wid * 5 + i;            // wave-uniform 0..19
            if (ci < 4) {
                const int row = ci * 16 + l4;
                if (mtile * 64 + ci * 16 + 16 <= M)    // wave-uniform (M%16==0)
                    gload_lds16(A + (size_t)(mtile * 64 + row) * K + k0 + schunk * 8,
                                &As2[b][ci * 512]);
            } else {
                const int cb  = ci - 4;
                const int row = cb * 16 + l4;
                gload_lds16(Wt + (size_t)(ntile * 256 + row) * K + k0 + schunk * 8,
                            &Bs2[b][cb * 512]);
            }
        }
    };

    const int NT = K >> 5;
    stage(0, 0);
    __syncthreads();   // buf0 ready

    for (int t = 0; t < NT; ++t) {
        const int cur = t & 1;
        if (t + 1 < NT) stage(cur ^ 1, (t + 1) << 5);   // overlaps compute below
        // compute buf[cur]: read swizzle chunk' = c ^ ((row>>1)&3), c = lane>>4
        const int rsw = ((lane >> 1) & 3);              // (row>>1)&3 with row=lane&15
        const int coff = ((lane >> 4) ^ rsw) << 3;      // element offset in 32-row
        short8 a[4], b[4];
        #pragma unroll
        for (int m = 0; m < 4; ++m)
            a[m] = *reinterpret_cast<const short8*>(
                &As2[cur][(m * 16 + (lane & 15)) * 32 + coff]);
        #pragma unroll
        for (int n = 0; n < 4; ++n)
            b[n] = *reinterpret_cast<const short8*>(
                &Bs2[cur][(wid * 64 + n * 16 + (lane & 15)) * 32 + coff]);
        #pragma unroll
        for (int m = 0; m < 4; ++m)
            #pragma unroll
            for (int n = 0; n < 4; ++n)
                acc[m][n] = __builtin_amdgcn_mfma_f32_16x16x32_bf16(
                    a[m], b[n], acc[m][n], 0, 0, 0);
        __syncthreads();   // cur reads done + next buf drained
    }

    // epilogue: C/D layout col=lane&15, row=(lane>>4)*4+reg
    TO* Cp = C + (size_t)ntile * PS;   // plane base
    if constexpr (is_same_t<TO, bf16>::v) {
        // per-wave private 8KB bounce region in the (now dead) Bs2
        short* eb = (short*)Bs2 + wid * 4096;
        #pragma unroll
        for (int m = 0; m < 4; ++m)
            #pragma unroll
            for (int n = 0; n < 4; ++n) {
                int col_l = n * 16 + (lane & 15);
                float bcol = bias[ntile * 256 + wid * 64 + col_l];
                #pragma unroll
                for (int r = 0; r < 4; ++r) {
                    int row_l = m * 16 + ((lane >> 4) << 2) + r;
                    float val = acc[m][n][r] + bcol;
                    if (ACT == 1) val = tanhf(val);
                    if (ACT == 2) val = fmaxf(val, 0.f);
                    eb[row_l * 64 + (col_l ^ ((row_l & 7) << 3))] = (short)f2bu(val);
                }
            }
        // read back coalesced: 8 lanes per row, 16B per lane (wave-private)
        #pragma unroll
        for (int i = 0; i < 8; ++i) {
            int row_l = i * 8 + (lane >> 3);
            int row_g = mtile * 64 + row_l;
            short8 vr = *reinterpret_cast<const short8*>(
                &eb[row_l * 64 + ((((lane & 7) << 3)) ^ ((row_l & 7) << 3))]);
            if (row_g < M)
                *reinterpret_cast<short8*>(
                    &Cp[(size_t)row_g * 256 + wid * 64 + ((lane & 7) << 3)]) = vr;
        }
    } else {
        #pragma unroll
        for (int m = 0; m < 4; ++m) {
            int row0 = mtile * 64 + m * 16 + ((lane >> 4) << 2);
            #pragma unroll
            for (int n = 0; n < 4; ++n) {
                int col_l = wid * 64 + n * 16 + (lane & 15);
                float bcol = bias[ntile * 256 + col_l];
                #pragma unroll
                for (int r = 0; r < 4; ++r) {
                    int row = row0 + r;
                    if (row < M) {
                        float val = acc[m][n][r] + bcol;
                        if (ACT == 1) val = tanhf(val);
                        if (ACT == 2) val = fmaxf(val, 0.f);
                        if (res) val += ldf(&res[(size_t)row * 256 + col_l]);
                        stf(&Cp[(size_t)row * 256 + col_l], val);
                    }
                }
            }
        }
    }
}

// ================= CSR build =================
__global__ __launch_bounds__(256)
void hist_kernel(const int* __restrict__ dst, int* __restrict__ deg, int E)
{
    int e = blockIdx.x * 256 + threadIdx.x;
    if (e < E) atomicAdd(&deg[dst[e]], 1);
}

__global__ __launch_bounds__(256)
void scan1_kernel(const int* __restrict__ deg, int* __restrict__ part,
                  int* __restrict__ bsum, int n)
{
    __shared__ int sh[256];
    const int t = threadIdx.x;
    const int b0 = blockIdx.x * 1024;
    int v[4]; int s = 0;
    #pragma unroll
    for (int j = 0; j < 4; ++j) {
        int idx = b0 + t * 4 + j;
        v[j] = (idx < n) ? deg[idx] : 0;
        s += v[j];
    }
    sh[t] = s; __syncthreads();
    for (int off = 1; off < 256; off <<= 1) {
        int x = (t >= off) ? sh[t - off] : 0;
        __syncthreads();
        sh[t] += x;
        __syncthreads();
    }
    if (t == 255) bsum[blockIdx.x] = sh[255];
    int run = sh[t] - s;
    #pragma unroll
    for (int j = 0; j < 4; ++j) {
        int idx = b0 + t * 4 + j;
        if (idx < n) part[idx] = run;
        run += v[j];
    }
}

__global__ __launch_bounds__(256)
void scan2_kernel(const int* __restrict__ bsum, int* __restrict__ bsume, int nb)
{
    __shared__ int sh[256];
    const int t = threadIdx.x;
    int x0 = (t < nb) ? bsum[t] : 0;
    sh[t] = x0; __syncthreads();
    for (int off = 1; off < 256; off <<= 1) {
        int x = (t >= off) ? sh[t - off] : 0;
        __syncthreads();
        sh[t] += x;
        __syncthreads();
    }
    if (t < nb) bsume[t] = sh[t] - x0;
}

__global__ __launch_bounds__(256)
void scan3_kernel(int* __restrict__ rowptr, int* __restrict__ cursor,
                  const int* __restrict__ bsume, int n, int E)
{
    int idx = blockIdx.x * 256 + threadIdx.x;
    if (idx < n) {
        int val = rowptr[idx] + bsume[idx >> 10];
        rowptr[idx] = val;
        cursor[idx] = val;
    }
    if (idx == 0) rowptr[n] = E;
}

__global__ __launch_bounds__(256)
void scatter_kernel(const int* __restrict__ src, const int* __restrict__ dst,
                    int* __restrict__ cursor, int* __restrict__ esrc, int E)
{
    int e = blockIdx.x * 256 + threadIdx.x;
    if (e < E) {
        int slot = atomicAdd(&cursor[dst[e]], 1);
        esrc[slot] = src[e];
    }
}

// ================= fused flash-style attention (CSR gather, planes) ==========
// wave per dst node. q/k/v: compact [N,256] planes. out: [N,256] (out may == q:
// q[node] is read only by node's own wave before the write -> no race).
__global__ __launch_bounds__(256)
void attn_fused_kernel(const int* __restrict__ rowptr, const int* __restrict__ esrc,
                       const bf16* __restrict__ q, const bf16* __restrict__ k,
                       const bf16* __restrict__ v, bf16* __restrict__ out, int n)
{
    int node = blockIdx.x * 4 + (threadIdx.x >> 6);
    if (node >= n) return;
    int lane = threadIdx.x & 63;
    int lo = rowptr[node], hi = rowptr[node + 1];

    ushort4 qu = ((const ushort4*)(q + (size_t)node * 256))[lane];
    float q0 = bfu(qu.x), q1 = bfu(qu.y), q2 = bfu(qu.z), q3 = bfu(qu.w);

    float m = -INFINITY, s = 0.f;
    float a0 = 0.f, a1 = 0.f, a2 = 0.f, a3 = 0.f;
    for (int i = lo; i < hi; ++i) {
        int sn = esrc[i];
        ushort4 ku = ((const ushort4*)(k + (size_t)sn * 256))[lane];
        ushort4 vu = ((const ushort4*)(v + (size_t)sn * 256))[lane];
        float p = q0 * bfu(ku.x);
        p = fmaf(q1, bfu(ku.y), p);
        p = fmaf(q2, bfu(ku.z), p);
        p = fmaf(q3, bfu(ku.w), p);
        p += __shfl_xor(p, 1);
        p += __shfl_xor(p, 2);
        p += __shfl_xor(p, 4);
        p += __shfl_xor(p, 8);       // 16-lane group sum -> per-head dot
        float l = p * 0.125f;        // 1/sqrt(64)
        float mn = fmaxf(m, l);
        float sc = __expf(m - mn);
        float e  = __expf(l - mn);
        a0 = fmaf(a0, sc, e * bfu(vu.x));
        a1 = fmaf(a1, sc, e * bfu(vu.y));
        a2 = fmaf(a2, sc, e * bfu(vu.z));
        a3 = fmaf(a3, sc, e * bfu(vu.w));
        s  = s * sc + e;
        m  = mn;
    }
    float inv = 1.f / (s + 1e-16f);
    ushort4 o;
    o.x = f2bu(fmaxf(a0 * inv, 0.f));
    o.y = f2bu(fmaxf(a1 * inv, 0.f));
    o.z = f2bu(fmaxf(a2 * inv, 0.f));
    o.w = f2bu(fmaxf(a3 * inv, 0.f));
    ((ushort4*)(out + (size_t)node * 256))[lane] = o;
}

// ---------- per-channel BN stats (compact [M,256]) ----------
template<typename TX>
__global__ __launch_bounds__(256)
void col_stats_kernel(const TX* __restrict__ x, float* __restrict__ bnsum,
                      float* __restrict__ bnsumsq, int M)
{
    const int c = threadIdx.x;
    const int r0 = blockIdx.x * 64;
    const int r1 = min(r0 + 64, M);
    float ls = 0.f, lq = 0.f;
    for (int r = r0; r < r1; ++r) {
        float val = ldf(&x[(size_t)r * 256 + c]);
        ls += val;
        lq += val * val;
    }
    atomicAdd(&bnsum[c], ls);
    atomicAdd(&bnsumsq[c], lq);
}

// ---------- BN fold into following weights: Wt[n][k] *= scale[k] (in place),
// bout[n] = bin[n] + sum_k shift[k]*W; optionally export scale/shift ----------
__global__ __launch_bounds__(256)
void bn_fold_kernel(bf16* __restrict__ Wt, const float* __restrict__ bin,
                    float* __restrict__ bout,
                    const float* __restrict__ bnsum, const float* __restrict__ bnsumsq,
                    const float* __restrict__ g, const float* __restrict__ be,
                    float* __restrict__ s_out, float* __restrict__ t_out, float invM)
{
    __shared__ float sh[256];
    const int n = blockIdx.x, k = threadIdx.x;
    float mu  = bnsum[k] * invM;
    float var = bnsumsq[k] * invM - mu * mu;
    float scale = g[k] * rsqrtf(var + 1e-5f);
    float shift = be[k] - mu * scale;
    float w = ldf(&Wt[(size_t)n * 256 + k]);
    Wt[(size_t)n * 256 + k] = __float2bfloat16(w * scale);
    sh[k] = shift * w;
    __syncthreads();
    for (int off = 128; off; off >>= 1) {
        if (k < off) sh[k] += sh[k + off];
        __syncthreads();
    }
    if (k == 0) bout[n] = bin[n] + sh[0];
    if (s_out && n == 0) { s_out[k] = scale; t_out[k] = shift; }
}

// ---------- fused bn2 + residual + segment-mean pool ----------
// pooled[g][c] = cnt>0 ? (sc2*sum(a2) + s1*sum(h1))/cnt + sh2 + t1 : 0
__global__ __launch_bounds__(256)
void pool_bn_kernel(const bf16* __restrict__ a2, const bf16* __restrict__ h1,
                    const int* __restrict__ ibatch,
                    const float* __restrict__ bnsum, const float* __restrict__ bnsumsq,
                    const float* __restrict__ g2, const float* __restrict__ be2,
                    const float* __restrict__ s1, const float* __restrict__ t1,
                    float* __restrict__ out, float invM)
{
    int g = blockIdx.x;
    __shared__ int bounds[2];
    if (threadIdx.x == 0) {
        int lo = 0, hi = N_NODES;
        while (lo < hi) { int mid = (lo + hi) >> 1; if (ibatch[mid] < g) lo = mid + 1; else hi = mid; }
        bounds[0] = lo;
        int lo2 = lo, hi2 = N_NODES;
        while (lo2 < hi2) { int mid = (lo2 + hi2) >> 1; if (ibatch[mid] < g + 1) lo2 = mid + 1; else hi2 = mid; }
        bounds[1] = lo2;
    }
    __syncthreads();
    int lo = bounds[0], hi = bounds[1];
    int c = threadIdx.x;
    float sa = 0.f, sh = 0.f;
    for (int r = lo; r < hi; ++r) {
        sa += ldf(&a2[(size_t)r * 256 + c]);
        sh += ldf(&h1[(size_t)r * 256 + c]);
    }
    float mu  = bnsum[c] * invM;
    float var = bnsumsq[c] * invM - mu * mu;
    float sc2 = g2[c] * rsqrtf(var + 1e-5f);
    float sh2 = be2[c] - mu * sc2;
    int cnt = hi - lo;
    out[(size_t)g * 256 + c] =
        (cnt > 0) ? (sc2 * sa + s1[c] * sh) / cnt + sh2 + t1[c] : 0.f;
}

extern "C" void kernel_launch(void* const* d_in, const int* in_sizes, int n_in,
                              void* d_out, int out_size, void* d_ws, size_t ws_size,
                              hipStream_t stream)
{
    const float* drug_x  = (const float*)d_in[0];
    const int*   adj     = (const int*)  d_in[1];
    const int*   ibatch  = (const int*)  d_in[2];
    const float* cline_x = (const float*)d_in[3];
    const float* Wq1 = (const float*)d_in[4];  const float* bq1 = (const float*)d_in[5];
    const float* Wk1 = (const float*)d_in[6];  const float* bk1 = (const float*)d_in[7];
    const float* Wv1 = (const float*)d_in[8];  const float* bv1 = (const float*)d_in[9];
    const float* g1  = (const float*)d_in[10]; const float* be1 = (const float*)d_in[11];
    const float* Wq2 = (const float*)d_in[12]; const float* bq2 = (const float*)d_in[13];
    const float* Wk2 = (const float*)d_in[14]; const float* bk2 = (const float*)d_in[15];
    const float* Wv2 = (const float*)d_in[16]; const float* bv2 = (const float*)d_in[17];
    const float* g2  = (const float*)d_in[18]; const float* be2 = (const float*)d_in[19];
    const float* Wc1 = (const float*)d_in[20]; const float* bc1 = (const float*)d_in[21];
    const float* gc  = (const float*)d_in[22]; const float* bec = (const float*)d_in[23];
    const float* Wc2 = (const float*)d_in[24]; const float* bc2 = (const float*)d_in[25];

    const int* srcp = adj;
    const int* dstp = adj + N_EDGES;

    // ---- workspace arena (~209 MB) ----
    char* p = (char*)d_ws;
    auto take = [&p](size_t bytes) {
        char* r = p;
        p += (bytes + 15) & ~(size_t)15;
        return r;
    };
    const size_t PS = (size_t)N_NODES * 256;   // plane stride (elements)
    bf16*  qkv   = (bf16*)take(PS * 3 * sizeof(bf16));   // planes q|k|v; attn2 out in q-plane
    bf16*  h1    = (bf16*)take(PS * sizeof(bf16));       // drug_xb -> attnout1
    int*   rowptr= (int*)take((size_t)(N_NODES + 1) * sizeof(int));
    int*   degcur= (int*)take((size_t)N_NODES * sizeof(int));
    int*   bsum  = (int*)take(256 * sizeof(int));
    int*   bsume = (int*)take(256 * sizeof(int));
    int*   esrc  = (int*)take((size_t)N_EDGES * sizeof(int));
    float* bnsum = (float*)take(256 * sizeof(float));
    float* bnsumsq=(float*)take(256 * sizeof(float));
    float* s1buf = (float*)take(256 * sizeof(float));
    float* t1buf = (float*)take(256 * sizeof(float));
    bf16*  Wt1   = (bf16*)take((size_t)768 * 128 * sizeof(bf16));
    bf16*  Wt2   = (bf16*)take((size_t)768 * 256 * sizeof(bf16));
    bf16*  Wtc1  = (bf16*)take((size_t)256 * 960 * sizeof(bf16));
    bf16*  Wtc2  = (bf16*)take((size_t)256 * 256 * sizeof(bf16));
    float* bc2f  = (float*)take(256 * sizeof(float));
    float* bias1 = (float*)take(768 * sizeof(float));
    float* bias2 = (float*)take(768 * sizeof(float));
    size_t needed = (size_t)(p - (char*)d_ws);
    if (ws_size < needed) return;

    // aliases (lifetime-disjoint):
    bf16* drug_xb  = h1;                       // [N,128] bf16, dead before L1 attn writes
    bf16* cline_xb = qkv;                      // [2048,960] bf16 (qkv dead after pool)
    bf16* c1b      = qkv + (size_t)2048 * 960; // [2048,256] bf16 tanh output

    bf16* qpl = qkv;            // q plane
    bf16* kpl = qkv + PS;       // k plane
    bf16* vpl = qkv + 2 * PS;   // v plane

    float* out_pool = (float*)d_out;                      // [G,256]
    float* out_c    = out_pool + (size_t)N_GRAPH * OUT_C; // [B,256]

    dim3 gN(3, (N_NODES + 63) / 64);         // x = ntile (= plane)
    dim3 gB(1, B_CL / 64);
    const int nodeBlocks = (N_NODES + 3) / 4;

    // ===================== prep =====================
    convert_a_kernel<<<(N_NODES * 128 + 255) / 256, 256, 0, stream>>>(
        drug_x, drug_xb, DRUG_DIM, 128, N_NODES * 128);
    WtJobs jobs = {{
        { Wq1, Wt1, DRUG_DIM,   0, 128 },
        { Wk1, Wt1, DRUG_DIM, 256, 128 },
        { Wv1, Wt1, DRUG_DIM, 512, 128 },
        { Wq2, Wt2, 256,        0, 256 },
        { Wk2, Wt2, 256,      256, 256 },
        { Wv2, Wt2, 256,      512, 256 },
        { Wc1, Wtc1, CLINE_DIM, 0, 960 },
        { Wc2, Wtc2, 256,       0, 256 },
    }};
    convert_wt8_kernel<<<dim3(256, 8), 256, 0, stream>>>(jobs);
    concat3_kernel<<<3, 256, 0, stream>>>(bq1, bk1, bv1, bias1);
    concat3_kernel<<<3, 256, 0, stream>>>(bq2, bk2, bv2, bias2);

    // ===================== CSR build =====================
    hipMemsetAsync(degcur, 0, N_NODES * sizeof(int), stream);
    hist_kernel<<<(N_EDGES + 255) / 256, 256, 0, stream>>>(dstp, degcur, N_EDGES);
    const int NB1 = (N_NODES + 1023) / 1024;
    scan1_kernel<<<NB1, 256, 0, stream>>>(degcur, rowptr, bsum, N_NODES);
    scan2_kernel<<<1, 256, 0, stream>>>(bsum, bsume, NB1);
    scan3_kernel<<<(N_NODES + 255) / 256, 256, 0, stream>>>(rowptr, degcur, bsume, N_NODES, N_EDGES);
    scatter_kernel<<<(N_EDGES + 255) / 256, 256, 0, stream>>>(srcp, dstp, degcur, esrc, N_EDGES);

    // ===================== drug layer 1 =====================
    mfma_gemm_kernel<0, bf16><<<gN, 256, 0, stream>>>(
        drug_xb, Wt1, bias1, nullptr, qkv, N_NODES, 128, PS);
    // attnout1 (relu'd) -> compact [N,256] into h1 slot (drug_xb dead now)
    attn_fused_kernel<<<nodeBlocks, 256, 0, stream>>>(rowptr, esrc, qpl, kpl, vpl, h1, N_NODES);
    hipMemsetAsync(bnsum, 0, 512 * sizeof(float), stream);
    col_stats_kernel<bf16><<<(N_NODES + 63) / 64, 256, 0, stream>>>(h1, bnsum, bnsumsq, N_NODES);
    // fold BN1 into Wt2/bias2 (in place), export s1/t1 for the residual path
    bn_fold_kernel<<<768, 256, 0, stream>>>(Wt2, bias2, bias2, bnsum, bnsumsq,
                                            g1, be1, s1buf, t1buf, 1.0f / N_NODES);

    // ===================== drug layer 2 =====================
    mfma_gemm_kernel<0, bf16><<<gN, 256, 0, stream>>>(
        h1, Wt2, bias2, nullptr, qkv, N_NODES, 256, PS);
    // attnout2 -> in-place q-plane (compact)
    attn_fused_kernel<<<nodeBlocks, 256, 0, stream>>>(rowptr, esrc, qpl, kpl, vpl, qpl, N_NODES);
    hipMemsetAsync(bnsum, 0, 512 * sizeof(float), stream);
    col_stats_kernel<bf16><<<(N_NODES + 63) / 64, 256, 0, stream>>>(qpl, bnsum, bnsumsq, N_NODES);
    // fused: pooled = sc2*mean(attnout2) + s1*mean(attnout1) + sh2 + t1
    pool_bn_kernel<<<N_GRAPH, 256, 0, stream>>>(qpl, h1, ibatch, bnsum, bnsumsq,
                                                g2, be2, s1buf, t1buf, out_pool,
                                                1.0f / N_NODES);

    // ===================== cline branch (qkv region now dead) =====================
    convert_a_kernel<<<(B_CL * 960 + 255) / 256, 256, 0, stream>>>(
        cline_x, cline_xb, CLINE_DIM, 960, B_CL * 960);
    mfma_gemm_kernel<1, bf16><<<gB, 256, 0, stream>>>(
        cline_xb, Wtc1, bc1, nullptr, c1b, B_CL, 960, 0);          // tanh, bf16, plane0
    hipMemsetAsync(bnsum, 0, 512 * sizeof(float), stream);
    col_stats_kernel<bf16><<<(B_CL + 63) / 64, 256, 0, stream>>>(c1b, bnsum, bnsumsq, B_CL);
    bn_fold_kernel<<<256, 256, 0, stream>>>(Wtc2, bc2, bc2f, bnsum, bnsumsq,
                                            gc, bec, nullptr, nullptr, 1.0f / B_CL);
    // out_c = c1 + relu(c1 @ Wc2f^T + bc2f)
    mfma_gemm_kernel<2, float><<<gB, 256, 0, stream>>>(
        c1b, Wtc2, bc2f, c1b, out_c, B_CL, 256, 0);
}

// Round 13
// 609.977 us; speedup vs baseline: 1.0591x; 1.0591x over previous
//
#include <hip/hip_runtime.h>
#include <hip/hip_bf16.h>

// Problem constants (match reference)
static constexpr int N_NODES  = 100000;
static constexpr int N_EDGES  = 400000;
static constexpr int DRUG_DIM = 75;
static constexpr int OUT_C    = 256;   // OUT
static constexpr int N_GRAPH  = 2048;  // G
static constexpr int B_CL     = 2048;  // B
static constexpr int CLINE_DIM= 954;

using bf16 = __hip_bfloat16;
using short8 = __attribute__((ext_vector_type(8))) short;
using f32x4  = __attribute__((ext_vector_type(4))) float;

template<class A, class B> struct is_same_t { static constexpr bool v = false; };
template<class A> struct is_same_t<A, A>   { static constexpr bool v = true;  };

// ---------- load/store helpers ----------
__device__ __forceinline__ float ldf(const float* p) { return *p; }
__device__ __forceinline__ float ldf(const bf16* p)  { return __bfloat162float(*p); }
__device__ __forceinline__ void  stf(float* p, float v) { *p = v; }
__device__ __forceinline__ void  stf(bf16* p, float v)  { *p = __float2bfloat16(v); }
__device__ __forceinline__ float bfu(unsigned short u) { return __uint_as_float(((unsigned)u) << 16); }
__device__ __forceinline__ unsigned short f2bu(float f) {
    bf16 h = __float2bfloat16(f);
    return *reinterpret_cast<unsigned short*>(&h);
}

// async global -> LDS, 16B per lane; LDS dest = uniform base + lane*16
__device__ __forceinline__ void gload_lds16(const void* g, void* l) {
    __builtin_amdgcn_global_load_lds(
        (const __attribute__((address_space(1))) void*)g,
        (__attribute__((address_space(3))) void*)l, 16, 0, 0);
}

// ================= input/weight prep =================
__global__ __launch_bounds__(256)
void convert_a_kernel(const float* __restrict__ A, bf16* __restrict__ Ab,
                      int K, int Kpad, int total)
{
    int idx = blockIdx.x * 256 + threadIdx.x;
    if (idx >= total) return;
    int r = idx / Kpad, k = idx - r * Kpad;
    float f = (k < K) ? A[(size_t)r * K + k] : 0.f;
    Ab[idx] = __float2bfloat16(f);
}

// all weight transposes in one launch; NW is always 256
struct WtJob  { const float* W; bf16* Wt; int K; int n0; int Kpad; };
struct WtJobs { WtJob j[8]; };
__global__ __launch_bounds__(256)
void convert_wt8_kernel(WtJobs jobs)
{
    WtJob jb = jobs.j[blockIdx.y];
    int n = blockIdx.x;
    for (int k = threadIdx.x; k < jb.Kpad; k += 256) {
        float f = (k < jb.K) ? jb.W[(size_t)k * 256 + n] : 0.f;
        jb.Wt[(size_t)(jb.n0 + n) * jb.Kpad + k] = __float2bfloat16(f);
    }
}

__global__ __launch_bounds__(256)
void concat3_kernel(const float* __restrict__ a, const float* __restrict__ b,
                    const float* __restrict__ c, float* __restrict__ out)
{
    int i = blockIdx.x * 256 + threadIdx.x;
    if (i < 256)      out[i] = a[i];
    else if (i < 512) out[i] = b[i - 256];
    else if (i < 768) out[i] = c[i - 512];
}

// ================= MFMA GEMM (single-buffer global_load_lds, 64x256 tile) =====
// 1D grid with XCD-aware bijective swizzle (8 XCDs, m204 formula): hardware
// assigns block id round-robin to XCDs (xcd = id%8); we remap so each XCD
// executes a CONTIGUOUS wgid range with ntile varying fastest -> the 3 blocks
// sharing an A-tile run temporally adjacent on the SAME XCD L2.
// Plane-split output: column slab [ntile*256, +256) -> plane ntile of C:
// C + ntile*PS + row*256 + col. A bf16 [M][K], K mult of 64, M mult of 8.
// Tile 64x256, BK=64, 4 waves (1x4). LDS relation:
// LDS[row][y] = data[row][y ^ ((row&7)<<3)] via pre-swizzled global source.
template<int ACT, typename TO>
__global__ __launch_bounds__(256)
void mfma_gemm_kernel(const bf16* __restrict__ A, const bf16* __restrict__ Wt,
                      const float* __restrict__ bias, const bf16* __restrict__ res,
                      TO* __restrict__ C, int M, int K, size_t PS,
                      int NTILES, int nwg)
{
    __shared__ alignas(16) short As[64 * 64];    // 8 KB
    __shared__ alignas(16) short Bs[256 * 64];   // 32 KB

    // bijective XCD swizzle
    const int id  = blockIdx.x;
    const int qq  = nwg >> 3, rr = nwg & 7;
    const int xcd = id & 7, loc = id >> 3;
    const int wgid = (xcd < rr ? xcd * (qq + 1) : rr * (qq + 1) + (xcd - rr) * qq) + loc;
    const int ntile = wgid % NTILES, mtile = wgid / NTILES;

    const int tid = threadIdx.x;
    const int lane = tid & 63, wid = tid >> 6;   // wave col = wid (0..3)

    f32x4 acc[4][4] = {};

    for (int k0 = 0; k0 < K; k0 += 64) {
        // 40 staging issues (A: 8 chunks of 8 rows, B: 32 chunks), 10 per wave
        #pragma unroll
        for (int i = 0; i < 10; ++i) {
            const int ci = wid * 10 + i;               // wave-uniform
            if (ci < 8) {
                const int row = ci * 8 + (lane >> 3);
                const int e   = ((lane & 7) ^ (row & 7)) << 3;
                if (mtile * 64 + ci * 8 + 8 <= M)      // wave-uniform guard (M%8==0)
                    gload_lds16(A + (size_t)(mtile * 64 + row) * K + k0 + e,
                                &As[ci * 512]);
            } else {
                const int cb  = ci - 8;
                const int row = cb * 8 + (lane >> 3);
                const int e   = ((lane & 7) ^ (row & 7)) << 3;
                gload_lds16(Wt + (size_t)(ntile * 256 + row) * K + k0 + e,
                            &Bs[cb * 512]);
            }
        }
        __syncthreads();   // drains vmcnt(0): LDS tiles ready
        #pragma unroll
        for (int kk = 0; kk < 2; ++kk) {
            const int coff = (kk * 32 + (lane >> 4) * 8) ^ ((lane & 7) << 3);
            short8 a[4], b[4];
            #pragma unroll
            for (int m = 0; m < 4; ++m)
                a[m] = *reinterpret_cast<const short8*>(
                    &As[(m * 16 + (lane & 15)) * 64 + coff]);
            #pragma unroll
            for (int n = 0; n < 4; ++n)
                b[n] = *reinterpret_cast<const short8*>(
                    &Bs[(wid * 64 + n * 16 + (lane & 15)) * 64 + coff]);
            #pragma unroll
            for (int m = 0; m < 4; ++m)
                #pragma unroll
                for (int n = 0; n < 4; ++n)
                    acc[m][n] = __builtin_amdgcn_mfma_f32_16x16x32_bf16(
                        a[m], b[n], acc[m][n], 0, 0, 0);
        }
        __syncthreads();
    }

    // epilogue: C/D layout col=lane&15, row=(lane>>4)*4+reg
    TO* Cp = C + (size_t)ntile * PS;   // plane base
    if constexpr (is_same_t<TO, bf16>::v) {
        // per-wave private 8KB bounce region in the (now dead) Bs
        short* eb = Bs + wid * 4096;
        #pragma unroll
        for (int m = 0; m < 4; ++m)
            #pragma unroll
            for (int n = 0; n < 4; ++n) {
                int col_l = n * 16 + (lane & 15);
                float bcol = bias[ntile * 256 + wid * 64 + col_l];
                #pragma unroll
                for (int r = 0; r < 4; ++r) {
                    int row_l = m * 16 + ((lane >> 4) << 2) + r;
                    float val = acc[m][n][r] + bcol;
                    if (ACT == 1) val = tanhf(val);
                    if (ACT == 2) val = fmaxf(val, 0.f);
                    eb[row_l * 64 + (col_l ^ ((row_l & 7) << 3))] = (short)f2bu(val);
                }
            }
        // read back coalesced: 8 lanes per row, 16B per lane (wave-private)
        #pragma unroll
        for (int i = 0; i < 8; ++i) {
            int row_l = i * 8 + (lane >> 3);
            int row_g = mtile * 64 + row_l;
            short8 vr = *reinterpret_cast<const short8*>(
                &eb[row_l * 64 + ((((lane & 7) << 3)) ^ ((row_l & 7) << 3))]);
            if (row_g < M)
                *reinterpret_cast<short8*>(
                    &Cp[(size_t)row_g * 256 + wid * 64 + ((lane & 7) << 3)]) = vr;
        }
    } else {
        #pragma unroll
        for (int m = 0; m < 4; ++m) {
            int row0 = mtile * 64 + m * 16 + ((lane >> 4) << 2);
            #pragma unroll
            for (int n = 0; n < 4; ++n) {
                int col_l = wid * 64 + n * 16 + (lane & 15);
                float bcol = bias[ntile * 256 + col_l];
                #pragma unroll
                for (int r = 0; r < 4; ++r) {
                    int row = row0 + r;
                    if (row < M) {
                        float val = acc[m][n][r] + bcol;
                        if (ACT == 1) val = tanhf(val);
                        if (ACT == 2) val = fmaxf(val, 0.f);
                        if (res) val += ldf(&res[(size_t)row * 256 + col_l]);
                        stf(&Cp[(size_t)row * 256 + col_l], val);
                    }
                }
            }
        }
    }
}

// ================= CSR build =================
__global__ __launch_bounds__(256)
void hist_kernel(const int* __restrict__ dst, int* __restrict__ deg, int E)
{
    int e = blockIdx.x * 256 + threadIdx.x;
    if (e < E) atomicAdd(&deg[dst[e]], 1);
}

__global__ __launch_bounds__(256)
void scan1_kernel(const int* __restrict__ deg, int* __restrict__ part,
                  int* __restrict__ bsum, int n)
{
    __shared__ int sh[256];
    const int t = threadIdx.x;
    const int b0 = blockIdx.x * 1024;
    int v[4]; int s = 0;
    #pragma unroll
    for (int j = 0; j < 4; ++j) {
        int idx = b0 + t * 4 + j;
        v[j] = (idx < n) ? deg[idx] : 0;
        s += v[j];
    }
    sh[t] = s; __syncthreads();
    for (int off = 1; off < 256; off <<= 1) {
        int x = (t >= off) ? sh[t - off] : 0;
        __syncthreads();
        sh[t] += x;
        __syncthreads();
    }
    if (t == 255) bsum[blockIdx.x] = sh[255];
    int run = sh[t] - s;
    #pragma unroll
    for (int j = 0; j < 4; ++j) {
        int idx = b0 + t * 4 + j;
        if (idx < n) part[idx] = run;
        run += v[j];
    }
}

__global__ __launch_bounds__(256)
void scan2_kernel(const int* __restrict__ bsum, int* __restrict__ bsume, int nb)
{
    __shared__ int sh[256];
    const int t = threadIdx.x;
    int x0 = (t < nb) ? bsum[t] : 0;
    sh[t] = x0; __syncthreads();
    for (int off = 1; off < 256; off <<= 1) {
        int x = (t >= off) ? sh[t - off] : 0;
        __syncthreads();
        sh[t] += x;
        __syncthreads();
    }
    if (t < nb) bsume[t] = sh[t] - x0;
}

__global__ __launch_bounds__(256)
void scan3_kernel(int* __restrict__ rowptr, int* __restrict__ cursor,
                  const int* __restrict__ bsume, int n, int E)
{
    int idx = blockIdx.x * 256 + threadIdx.x;
    if (idx < n) {
        int val = rowptr[idx] + bsume[idx >> 10];
        rowptr[idx] = val;
        cursor[idx] = val;
    }
    if (idx == 0) rowptr[n] = E;
}

__global__ __launch_bounds__(256)
void scatter_kernel(const int* __restrict__ src, const int* __restrict__ dst,
                    int* __restrict__ cursor, int* __restrict__ esrc, int E)
{
    int e = blockIdx.x * 256 + threadIdx.x;
    if (e < E) {
        int slot = atomicAdd(&cursor[dst[e]], 1);
        esrc[slot] = src[e];
    }
}

// ================= fused flash-style attention (CSR gather, planes) ==========
// wave per dst node. q/k/v: compact [N,256] planes. out: [N,256] (out may == q:
// q[node] is read only by node's own wave before the write -> no race).
// 2-edge unroll: 4 independent 16B gathers in flight per iteration.
// Branchy rescale: numerically IDENTICAL to always-rescale (sc==1 when no new
// max) but skips ~8 VALU ops on the ~(1 - ln(deg)/deg) of edges with no new max.
__global__ __launch_bounds__(256)
void attn_fused_kernel(const int* __restrict__ rowptr, const int* __restrict__ esrc,
                       const bf16* __restrict__ q, const bf16* __restrict__ k,
                       const bf16* __restrict__ v, bf16* __restrict__ out, int n)
{
    int node = blockIdx.x * 4 + (threadIdx.x >> 6);
    if (node >= n) return;
    int lane = threadIdx.x & 63;
    int lo = rowptr[node], hi = rowptr[node + 1];

    ushort4 qu = ((const ushort4*)(q + (size_t)node * 256))[lane];
    float q0 = bfu(qu.x), q1 = bfu(qu.y), q2 = bfu(qu.z), q3 = bfu(qu.w);

    float m = -INFINITY, s = 0.f;
    float a0 = 0.f, a1 = 0.f, a2 = 0.f, a3 = 0.f;

    auto upd = [&](float l, ushort4 vu) {
        if (l > m) {                       // new max: rescale (uniform per head group)
            float sc = __expf(m - l);      // exp(-inf)=0 handles first edge
            a0 *= sc; a1 *= sc; a2 *= sc; a3 *= sc; s *= sc;
            m = l;
        }
        float e = __expf(l - m);
        a0 = fmaf(e, bfu(vu.x), a0);
        a1 = fmaf(e, bfu(vu.y), a1);
        a2 = fmaf(e, bfu(vu.z), a2);
        a3 = fmaf(e, bfu(vu.w), a3);
        s += e;
    };

    int i = lo;
    for (; i + 2 <= hi; i += 2) {
        int sn0 = esrc[i], sn1 = esrc[i + 1];
        ushort4 ku0 = ((const ushort4*)(k + (size_t)sn0 * 256))[lane];
        ushort4 vu0 = ((const ushort4*)(v + (size_t)sn0 * 256))[lane];
        ushort4 ku1 = ((const ushort4*)(k + (size_t)sn1 * 256))[lane];
        ushort4 vu1 = ((const ushort4*)(v + (size_t)sn1 * 256))[lane];
        float p0 = q0 * bfu(ku0.x);
        p0 = fmaf(q1, bfu(ku0.y), p0);
        p0 = fmaf(q2, bfu(ku0.z), p0);
        p0 = fmaf(q3, bfu(ku0.w), p0);
        float p1 = q0 * bfu(ku1.x);
        p1 = fmaf(q1, bfu(ku1.y), p1);
        p1 = fmaf(q2, bfu(ku1.z), p1);
        p1 = fmaf(q3, bfu(ku1.w), p1);
        p0 += __shfl_xor(p0, 1);  p1 += __shfl_xor(p1, 1);
        p0 += __shfl_xor(p0, 2);  p1 += __shfl_xor(p1, 2);
        p0 += __shfl_xor(p0, 4);  p1 += __shfl_xor(p1, 4);
        p0 += __shfl_xor(p0, 8);  p1 += __shfl_xor(p1, 8);
        upd(p0 * 0.125f, vu0);
        upd(p1 * 0.125f, vu1);
    }
    if (i < hi) {
        int sn = esrc[i];
        ushort4 ku = ((const ushort4*)(k + (size_t)sn * 256))[lane];
        ushort4 vu = ((const ushort4*)(v + (size_t)sn * 256))[lane];
        float p = q0 * bfu(ku.x);
        p = fmaf(q1, bfu(ku.y), p);
        p = fmaf(q2, bfu(ku.z), p);
        p = fmaf(q3, bfu(ku.w), p);
        p += __shfl_xor(p, 1);
        p += __shfl_xor(p, 2);
        p += __shfl_xor(p, 4);
        p += __shfl_xor(p, 8);
        upd(p * 0.125f, vu);
    }

    float inv = 1.f / (s + 1e-16f);
    ushort4 o;
    o.x = f2bu(fmaxf(a0 * inv, 0.f));
    o.y = f2bu(fmaxf(a1 * inv, 0.f));
    o.z = f2bu(fmaxf(a2 * inv, 0.f));
    o.w = f2bu(fmaxf(a3 * inv, 0.f));
    ((ushort4*)(out + (size_t)node * 256))[lane] = o;
}

// ---------- per-channel BN stats (compact [M,256]) ----------
template<typename TX>
__global__ __launch_bounds__(256)
void col_stats_kernel(const TX* __restrict__ x, float* __restrict__ bnsum,
                      float* __restrict__ bnsumsq, int M)
{
    const int c = threadIdx.x;
    const int r0 = blockIdx.x * 64;
    const int r1 = min(r0 + 64, M);
    float ls = 0.f, lq = 0.f;
    for (int r = r0; r < r1; ++r) {
        float val = ldf(&x[(size_t)r * 256 + c]);
        ls += val;
        lq += val * val;
    }
    atomicAdd(&bnsum[c], ls);
    atomicAdd(&bnsumsq[c], lq);
}

// ---------- BN fold into following weights: Wt[n][k] *= scale[k] (in place),
// bout[n] = bin[n] + sum_k shift[k]*W; optionally export scale/shift ----------
__global__ __launch_bounds__(256)
void bn_fold_kernel(bf16* __restrict__ Wt, const float* __restrict__ bin,
                    float* __restrict__ bout,
                    const float* __restrict__ bnsum, const float* __restrict__ bnsumsq,
                    const float* __restrict__ g, const float* __restrict__ be,
                    float* __restrict__ s_out, float* __restrict__ t_out, float invM)
{
    __shared__ float sh[256];
    const int n = blockIdx.x, k = threadIdx.x;
    float mu  = bnsum[k] * invM;
    float var = bnsumsq[k] * invM - mu * mu;
    float scale = g[k] * rsqrtf(var + 1e-5f);
    float shift = be[k] - mu * scale;
    float w = ldf(&Wt[(size_t)n * 256 + k]);
    Wt[(size_t)n * 256 + k] = __float2bfloat16(w * scale);
    sh[k] = shift * w;
    __syncthreads();
    for (int off = 128; off; off >>= 1) {
        if (k < off) sh[k] += sh[k + off];
        __syncthreads();
    }
    if (k == 0) bout[n] = bin[n] + sh[0];
    if (s_out && n == 0) { s_out[k] = scale; t_out[k] = shift; }
}

// ---------- fused bn2 + residual + segment-mean pool ----------
// pooled[g][c] = cnt>0 ? (sc2*sum(a2) + s1*sum(h1))/cnt + sh2 + t1 : 0
__global__ __launch_bounds__(256)
void pool_bn_kernel(const bf16* __restrict__ a2, const bf16* __restrict__ h1,
                    const int* __restrict__ ibatch,
                    const float* __restrict__ bnsum, const float* __restrict__ bnsumsq,
                    const float* __restrict__ g2, const float* __restrict__ be2,
                    const float* __restrict__ s1, const float* __restrict__ t1,
                    float* __restrict__ out, float invM)
{
    int g = blockIdx.x;
    __shared__ int bounds[2];
    if (threadIdx.x == 0) {
        int lo = 0, hi = N_NODES;
        while (lo < hi) { int mid = (lo + hi) >> 1; if (ibatch[mid] < g) lo = mid + 1; else hi = mid; }
        bounds[0] = lo;
        int lo2 = lo, hi2 = N_NODES;
        while (lo2 < hi2) { int mid = (lo2 + hi2) >> 1; if (ibatch[mid] < g + 1) lo2 = mid + 1; else hi2 = mid; }
        bounds[1] = lo2;
    }
    __syncthreads();
    int lo = bounds[0], hi = bounds[1];
    int c = threadIdx.x;
    float sa = 0.f, sh = 0.f;
    for (int r = lo; r < hi; ++r) {
        sa += ldf(&a2[(size_t)r * 256 + c]);
        sh += ldf(&h1[(size_t)r * 256 + c]);
    }
    float mu  = bnsum[c] * invM;
    float var = bnsumsq[c] * invM - mu * mu;
    float sc2 = g2[c] * rsqrtf(var + 1e-5f);
    float sh2 = be2[c] - mu * sc2;
    int cnt = hi - lo;
    out[(size_t)g * 256 + c] =
        (cnt > 0) ? (sc2 * sa + s1[c] * sh) / cnt + sh2 + t1[c] : 0.f;
}

extern "C" void kernel_launch(void* const* d_in, const int* in_sizes, int n_in,
                              void* d_out, int out_size, void* d_ws, size_t ws_size,
                              hipStream_t stream)
{
    const float* drug_x  = (const float*)d_in[0];
    const int*   adj     = (const int*)  d_in[1];
    const int*   ibatch  = (const int*)  d_in[2];
    const float* cline_x = (const float*)d_in[3];
    const float* Wq1 = (const float*)d_in[4];  const float* bq1 = (const float*)d_in[5];
    const float* Wk1 = (const float*)d_in[6];  const float* bk1 = (const float*)d_in[7];
    const float* Wv1 = (const float*)d_in[8];  const float* bv1 = (const float*)d_in[9];
    const float* g1  = (const float*)d_in[10]; const float* be1 = (const float*)d_in[11];
    const float* Wq2 = (const float*)d_in[12]; const float* bq2 = (const float*)d_in[13];
    const float* Wk2 = (const float*)d_in[14]; const float* bk2 = (const float*)d_in[15];
    const float* Wv2 = (const float*)d_in[16]; const float* bv2 = (const float*)d_in[17];
    const float* g2  = (const float*)d_in[18]; const float* be2 = (const float*)d_in[19];
    const float* Wc1 = (const float*)d_in[20]; const float* bc1 = (const float*)d_in[21];
    const float* gc  = (const float*)d_in[22]; const float* bec = (const float*)d_in[23];
    const float* Wc2 = (const float*)d_in[24]; const float* bc2 = (const float*)d_in[25];

    const int* srcp = adj;
    const int* dstp = adj + N_EDGES;

    // ---- workspace arena (~209 MB) ----
    char* p = (char*)d_ws;
    auto take = [&p](size_t bytes) {
        char* r = p;
        p += (bytes + 15) & ~(size_t)15;
        return r;
    };
    const size_t PS = (size_t)N_NODES * 256;   // plane stride (elements)
    bf16*  qkv   = (bf16*)take(PS * 3 * sizeof(bf16));   // planes q|k|v; attn2 out in q-plane
    bf16*  h1    = (bf16*)take(PS * sizeof(bf16));       // drug_xb -> attnout1
    int*   rowptr= (int*)take((size_t)(N_NODES + 1) * sizeof(int));
    int*   degcur= (int*)take((size_t)N_NODES * sizeof(int));
    int*   bsum  = (int*)take(256 * sizeof(int));
    int*   bsume = (int*)take(256 * sizeof(int));
    int*   esrc  = (int*)take((size_t)N_EDGES * sizeof(int));
    float* bnsum = (float*)take(256 * sizeof(float));
    float* bnsumsq=(float*)take(256 * sizeof(float));
    float* s1buf = (float*)take(256 * sizeof(float));
    float* t1buf = (float*)take(256 * sizeof(float));
    bf16*  Wt1   = (bf16*)take((size_t)768 * 128 * sizeof(bf16));
    bf16*  Wt2   = (bf16*)take((size_t)768 * 256 * sizeof(bf16));
    bf16*  Wtc1  = (bf16*)take((size_t)256 * 960 * sizeof(bf16));
    bf16*  Wtc2  = (bf16*)take((size_t)256 * 256 * sizeof(bf16));
    float* bc2f  = (float*)take(256 * sizeof(float));
    float* bias1 = (float*)take(768 * sizeof(float));
    float* bias2 = (float*)take(768 * sizeof(float));
    size_t needed = (size_t)(p - (char*)d_ws);
    if (ws_size < needed) return;

    // aliases (lifetime-disjoint):
    bf16* drug_xb  = h1;                       // [N,128] bf16, dead before L1 attn writes
    bf16* cline_xb = qkv;                      // [2048,960] bf16 (qkv dead after pool)
    bf16* c1b      = qkv + (size_t)2048 * 960; // [2048,256] bf16 tanh output

    bf16* qpl = qkv;            // q plane
    bf16* kpl = qkv + PS;       // k plane
    bf16* vpl = qkv + 2 * PS;   // v plane

    float* out_pool = (float*)d_out;                      // [G,256]
    float* out_c    = out_pool + (size_t)N_GRAPH * OUT_C; // [B,256]

    const int MT_N = (N_NODES + 63) / 64;    // 1563 mtiles
    const int nwgN = 3 * MT_N;               // drug GEMM: ntile fastest in wgid
    const int nwgB = B_CL / 64;              // 32 (NTILES=1)
    const int nodeBlocks = (N_NODES + 3) / 4;

    // ===================== prep =====================
    convert_a_kernel<<<(N_NODES * 128 + 255) / 256, 256, 0, stream>>>(
        drug_x, drug_xb, DRUG_DIM, 128, N_NODES * 128);
    WtJobs jobs = {{
        { Wq1, Wt1, DRUG_DIM,   0, 128 },
        { Wk1, Wt1, DRUG_DIM, 256, 128 },
        { Wv1, Wt1, DRUG_DIM, 512, 128 },
        { Wq2, Wt2, 256,        0, 256 },
        { Wk2, Wt2, 256,      256, 256 },
        { Wv2, Wt2, 256,      512, 256 },
        { Wc1, Wtc1, CLINE_DIM, 0, 960 },
        { Wc2, Wtc2, 256,       0, 256 },
    }};
    convert_wt8_kernel<<<dim3(256, 8), 256, 0, stream>>>(jobs);
    concat3_kernel<<<3, 256, 0, stream>>>(bq1, bk1, bv1, bias1);
    concat3_kernel<<<3, 256, 0, stream>>>(bq2, bk2, bv2, bias2);

    // ===================== CSR build =====================
    hipMemsetAsync(degcur, 0, N_NODES * sizeof(int), stream);
    hist_kernel<<<(N_EDGES + 255) / 256, 256, 0, stream>>>(dstp, degcur, N_EDGES);
    const int NB1 = (N_NODES + 1023) / 1024;
    scan1_kernel<<<NB1, 256, 0, stream>>>(degcur, rowptr, bsum, N_NODES);
    scan2_kernel<<<1, 256, 0, stream>>>(bsum, bsume, NB1);
    scan3_kernel<<<(N_NODES + 255) / 256, 256, 0, stream>>>(rowptr, degcur, bsume, N_NODES, N_EDGES);
    scatter_kernel<<<(N_EDGES + 255) / 256, 256, 0, stream>>>(srcp, dstp, degcur, esrc, N_EDGES);

    // ===================== drug layer 1 =====================
    mfma_gemm_kernel<0, bf16><<<nwgN, 256, 0, stream>>>(
        drug_xb, Wt1, bias1, nullptr, qkv, N_NODES, 128, PS, 3, nwgN);
    // attnout1 (relu'd) -> compact [N,256] into h1 slot (drug_xb dead now)
    attn_fused_kernel<<<nodeBlocks, 256, 0, stream>>>(rowptr, esrc, qpl, kpl, vpl, h1, N_NODES);
    hipMemsetAsync(bnsum, 0, 512 * sizeof(float), stream);
    col_stats_kernel<bf16><<<(N_NODES + 63) / 64, 256, 0, stream>>>(h1, bnsum, bnsumsq, N_NODES);
    // fold BN1 into Wt2/bias2 (in place), export s1/t1 for the residual path
    bn_fold_kernel<<<768, 256, 0, stream>>>(Wt2, bias2, bias2, bnsum, bnsumsq,
                                            g1, be1, s1buf, t1buf, 1.0f / N_NODES);

    // ===================== drug layer 2 =====================
    mfma_gemm_kernel<0, bf16><<<nwgN, 256, 0, stream>>>(
        h1, Wt2, bias2, nullptr, qkv, N_NODES, 256, PS, 3, nwgN);
    // attnout2 -> in-place q-plane (compact)
    attn_fused_kernel<<<nodeBlocks, 256, 0, stream>>>(rowptr, esrc, qpl, kpl, vpl, qpl, N_NODES);
    hipMemsetAsync(bnsum, 0, 512 * sizeof(float), stream);
    col_stats_kernel<bf16><<<(N_NODES + 63) / 64, 256, 0, stream>>>(qpl, bnsum, bnsumsq, N_NODES);
    // fused: pooled = sc2*mean(attnout2) + s1*mean(attnout1) + sh2 + t1
    pool_bn_kernel<<<N_GRAPH, 256, 0, stream>>>(qpl, h1, ibatch, bnsum, bnsumsq,
                                                g2, be2, s1buf, t1buf, out_pool,
                                                1.0f / N_NODES);

    // ===================== cline branch (qkv region now dead) =====================
    convert_a_kernel<<<(B_CL * 960 + 255) / 256, 256, 0, stream>>>(
        cline_x, cline_xb, CLINE_DIM, 960, B_CL * 960);
    mfma_gemm_kernel<1, bf16><<<nwgB, 256, 0, stream>>>(
        cline_xb, Wtc1, bc1, nullptr, c1b, B_CL, 960, 0, 1, nwgB);  // tanh, bf16
    hipMemsetAsync(bnsum, 0, 512 * sizeof(float), stream);
    col_stats_kernel<bf16><<<(B_CL + 63) / 64, 256, 0, stream>>>(c1b, bnsum, bnsumsq, B_CL);
    bn_fold_kernel<<<256, 256, 0, stream>>>(Wtc2, bc2, bc2f, bnsum, bnsumsq,
                                            gc, bec, nullptr, nullptr, 1.0f / B_CL);
    // out_c = c1 + relu(c1 @ Wc2f^T + bc2f)
    mfma_gemm_kernel<2, float><<<nwgB, 256, 0, stream>>>(
        c1b, Wtc2, bc2f, c1b, out_c, B_CL, 256, 0, 1, nwgB);
}